// Round 6
// baseline (202.720 us; speedup 1.0000x reference)
//
#include <hip/hip_runtime.h>

typedef unsigned short u16;
typedef __bf16 bf16x8 __attribute__((ext_vector_type(8)));
typedef float f32x4 __attribute__((ext_vector_type(4)));

#define S_LEN 2048
#define EMB   1024
#define NHEAD 16
#define HDIM  64
#define WIN   1024

__device__ __forceinline__ u16 f2bf(float f) {
  unsigned u = __float_as_uint(f);
  u += 0x7FFFu + ((u >> 16) & 1u);   // round-to-nearest-even
  return (u16)(u >> 16);
}

// ---------------- fp32 -> bf16 conversion: 7 tensors, one launch ----------
__global__ __launch_bounds__(256) void conv_kernel(
    const float* __restrict__ p0, const float* __restrict__ p1,
    const float* __restrict__ p2, const float* __restrict__ p3,
    const float* __restrict__ p4, const float* __restrict__ p5,
    const float* __restrict__ p6,
    u16* __restrict__ o0, u16* __restrict__ o1, u16* __restrict__ o2,
    u16* __restrict__ o3, u16* __restrict__ o4, u16* __restrict__ o5,
    u16* __restrict__ o6) {
  const float* src; u16* dst; int n;
  switch (blockIdx.y) {
    case 0: src = p0; dst = o0; n = S_LEN * EMB; break;
    case 1: src = p1; dst = o1; n = S_LEN * EMB; break;
    case 2: src = p2; dst = o2; n = S_LEN * EMB; break;
    case 3: src = p3; dst = o3; n = EMB * EMB; break;
    case 4: src = p4; dst = o4; n = EMB * EMB; break;
    case 5: src = p5; dst = o5; n = EMB * EMB; break;
    default: src = p6; dst = o6; n = EMB * EMB; break;
  }
  int i = (blockIdx.x * 256 + threadIdx.x) * 4;
  if (i >= n) return;
  float4 v = *reinterpret_cast<const float4*>(src + i);
  ushort4 r;
  r.x = f2bf(v.x); r.y = f2bf(v.y); r.z = f2bf(v.z); r.w = f2bf(v.w);
  *reinterpret_cast<ushort4*>(dst + i) = r;
}

// ---------------- bf16 GEMM core: C[M,N] = A[M,K] @ W[N,K]^T --------------
// headMajor: bf16 out in [H][S][D] layout (for attention operand locality).
__device__ __forceinline__ void gemm128_core(
    const u16* __restrict__ A, const u16* __restrict__ W,
    const float* __restrict__ bias, float scale, int headMajor,
    u16* __restrict__ outB, float* __restrict__ outF0, float* __restrict__ outF1,
    int N, int K, int bm, int bn, u16* As, u16* Bs) {
  const int tid  = threadIdx.x;
  const int w    = tid >> 6;
  const int lane = tid & 63;
  const int wr = w >> 1, wc = w & 1;
  const int lr = lane & 15;
  const int ko = (lane >> 4) * 8;

  f32x4 acc[4][4];
#pragma unroll
  for (int i = 0; i < 4; ++i)
#pragma unroll
    for (int j = 0; j < 4; ++j) acc[i][j] = f32x4{0.f, 0.f, 0.f, 0.f};

  const int srow = lane >> 3;        // 0..7
  const int scol = (lane & 7) * 8;   // 0..56

  for (int k0 = 0; k0 < K; k0 += 64) {
    const u16* Ab = A + (size_t)bm * K + k0;
    const u16* Wb = W + (size_t)bn * K + k0;
#pragma unroll
    for (int c = 0; c < 4; ++c) {
      int s = w * 4 + c;
      __builtin_amdgcn_global_load_lds(
          (const __attribute__((address_space(1))) void*)(Ab + (size_t)(s * 8 + srow) * K + scol),
          (__attribute__((address_space(3))) void*)(As + s * 512), 16, 0, 0);
      __builtin_amdgcn_global_load_lds(
          (const __attribute__((address_space(1))) void*)(Wb + (size_t)(s * 8 + srow) * K + scol),
          (__attribute__((address_space(3))) void*)(Bs + s * 512), 16, 0, 0);
    }
    __syncthreads();
#pragma unroll
    for (int kk = 0; kk < 2; ++kk) {
      bf16x8 af[4], bfr[4];
#pragma unroll
      for (int mi = 0; mi < 4; ++mi)
        af[mi] = *reinterpret_cast<const bf16x8*>(&As[(wr * 64 + mi * 16 + lr) * 64 + kk * 32 + ko]);
#pragma unroll
      for (int ni = 0; ni < 4; ++ni)
        bfr[ni] = *reinterpret_cast<const bf16x8*>(&Bs[(wc * 64 + ni * 16 + lr) * 64 + kk * 32 + ko]);
#pragma unroll
      for (int mi = 0; mi < 4; ++mi)
#pragma unroll
        for (int ni = 0; ni < 4; ++ni)
          acc[mi][ni] = __builtin_amdgcn_mfma_f32_16x16x32_bf16(af[mi], bfr[ni], acc[mi][ni], 0, 0, 0);
    }
    __syncthreads();
  }

  const int cr = (lane >> 4) * 4;
  const int cc = lane & 15;
#pragma unroll
  for (int mi = 0; mi < 4; ++mi) {
#pragma unroll
    for (int ni = 0; ni < 4; ++ni) {
      int col = bn + wc * 64 + ni * 16 + cc;
      float bv = bias[col];
#pragma unroll
      for (int r = 0; r < 4; ++r) {
        int row = bm + wr * 64 + mi * 16 + cr + r;
        float val = (acc[mi][ni][r] + bv) * scale;
        if (outB) {
          size_t idx = headMajor
              ? (size_t)(col >> 6) * (S_LEN * HDIM) + (size_t)row * HDIM + (col & 63)
              : (size_t)row * N + col;
          outB[idx] = f2bf(val);
        } else {
          outF0[(size_t)row * N + col] = val;
          outF1[(size_t)row * N + col] = val;
        }
      }
    }
  }
}

// z=0: Q (head-major, pre-scaled 1/64); z=1: K (head-major); z=2: V (token-major)
__global__ __launch_bounds__(256) void proj_gemm(
    const u16* __restrict__ Abase, const u16* __restrict__ Wbase,
    const float* __restrict__ b0, const float* __restrict__ b1,
    const float* __restrict__ b2, u16* __restrict__ Obase) {
  __shared__ u16 As[128 * 64];
  __shared__ u16 Bs[128 * 64];
  const int z = blockIdx.z;
  const u16* A = Abase + (size_t)z * (S_LEN * EMB);
  const u16* W = Wbase + (size_t)z * (EMB * EMB);
  const float* bias = (z == 0) ? b0 : (z == 1 ? b1 : b2);
  u16* O = Obase + (size_t)z * (S_LEN * EMB);
  float scale = (z == 0) ? (1.0f / 64.0f) : 1.0f;
  gemm128_core(A, W, bias, scale, (z < 2) ? 1 : 0, O, nullptr, nullptr,
               EMB, EMB, blockIdx.x * 128, blockIdx.y * 128, As, Bs);
}

__global__ __launch_bounds__(256) void out_gemm(
    const u16* __restrict__ A, const u16* __restrict__ W,
    const float* __restrict__ bias, float* __restrict__ out0,
    float* __restrict__ out1) {
  __shared__ u16 As[128 * 64];
  __shared__ u16 Bs[128 * 64];
  gemm128_core(A, W, bias, 1.0f, 0, nullptr, out0, out1,
               EMB, EMB, blockIdx.x * 128, blockIdx.y * 128, As, Bs);
}

// ---------------- V transpose: Vp[S,E] -> Vt[E,S] == [H][D][S] ------------
__global__ __launch_bounds__(256) void transpose_v(
    const u16* __restrict__ in, u16* __restrict__ out) {
  __shared__ u16 tile[32][33];
  const int bx = blockIdx.x * 32;  // E base
  const int by = blockIdx.y * 32;  // S base
  const int tr = threadIdx.x >> 5;
  const int tc = threadIdx.x & 31;
#pragma unroll
  for (int i = 0; i < 4; ++i)
    tile[tr + i * 8][tc] = in[(size_t)(by + tr + i * 8) * EMB + bx + tc];
  __syncthreads();
#pragma unroll
  for (int i = 0; i < 4; ++i)
    out[(size_t)(bx + tr + i * 8) * S_LEN + by + tc] = tile[tc][tr + i * 8];
}

// ---------------- flash attention: q-split waves, LDS-staged K/V ----------
// DIAGNOSTIC ROUND: blockIdx.z in [0,4) replicates the whole computation;
// z=0 writes the real output, z>0 write to dead scratch. This lifts the attn
// dispatch above the harness ws-fill dispatches so rocprof top-5 shows its
// counters, and tests occupancy sensitivity (z*4 -> 4 blocks/CU vs 2).
// Bias pipeline: bias(t+1) issued after the per-tile barrier, consumed only
// after the NEXT barrier (whose vmcnt-drain is the sync) -> softmax never
// waits on VMEM.
__global__ __launch_bounds__(256, 4) void attn_kernel(
    const u16* __restrict__ Qp, const u16* __restrict__ Kp,
    const u16* __restrict__ Vt, const float* __restrict__ pbias,
    u16* __restrict__ Ob, u16* __restrict__ Odummy) {
  __shared__ u16 KV[2][2][64 * 64];   // [buf][0=K tile / 1=V^T tile]
  __shared__ u16 Pb[4][16 * 64];      // per-wave P buffer (swizzled rows)

  const int tid  = threadIdx.x;
  const int w    = tid >> 6;
  const int lane = tid & 63;
  const int h  = blockIdx.y;
  const int q0 = (gridDim.x - 1 - blockIdx.x) * 64;  // long blocks first
  const int ql = lane & 15;
  const int g  = lane >> 4;
  const int qw = q0 + w * 16;              // this wave's q sub-tile base
  const int qg = qw + ql;                  // this lane's q row

  const u16* Kh  = Kp + (size_t)h * (S_LEN * HDIM);
  const u16* Vth = Vt + (size_t)h * (HDIM * S_LEN);

  // Q fragments (B-operand: col=q, k-elem d=g*8+j), head-major load
  const u16* Qrow = Qp + (size_t)h * (S_LEN * HDIM) + (size_t)qg * HDIM;
  bf16x8 qf0 = *reinterpret_cast<const bf16x8*>(&Qrow[g * 8]);
  bf16x8 qf1 = *reinterpret_cast<const bf16x8*>(&Qrow[32 + g * 8]);

  f32x4 o[4];
#pragma unroll
  for (int i = 0; i < 4; ++i) o[i] = f32x4{0.f, 0.f, 0.f, 0.f};
  float m = -1e30f, l = 0.f;

  const float* brow = pbias + (size_t)h * S_LEN * S_LEN + (size_t)qg * S_LEN + 4 * g;

  int kv_lo = q0 - WIN; if (kv_lo < 0) kv_lo = 0; kv_lo &= ~63;
  const int ntiles = ((q0 + 63 - kv_lo) >> 6) + 1;
  const int kv_last = kv_lo + (ntiles - 1) * 64;
  const int qw_hi = qw + 15;

  const int swz = (ql & 7) << 4;
  char* Prow = (char*)&Pb[w][0] + ql * 128;

  // stage K-tile + V^T-tile for kv0 into buf (wave w covers rows w*16..+15)
  auto STAGE = [&](int buf, int kv0) {
    u16* Kd = &KV[buf][0][(w * 16) * 64];
    u16* Vd = &KV[buf][1][(w * 16) * 64];
#pragma unroll
    for (int n = 0; n < 2; ++n) {
      int r  = w * 16 + n * 8 + (lane >> 3);
      int cp = (lane & 7) ^ (r & 7);
      __builtin_amdgcn_global_load_lds(
          (const __attribute__((address_space(1))) void*)(Kh + (size_t)(kv0 + r) * HDIM + cp * 8),
          (__attribute__((address_space(3))) void*)(Kd + n * 512), 16, 0, 0);
      __builtin_amdgcn_global_load_lds(
          (const __attribute__((address_space(1))) void*)(Vth + (size_t)r * S_LEN + kv0 + cp * 8),
          (__attribute__((address_space(3))) void*)(Vd + n * 512), 16, 0, 0);
    }
  };

  STAGE(0, kv_lo);
  // issue bias(tile 0); lands before the first barrier's vmcnt drain
  float4 nb[4], cb[4];
#pragma unroll
  for (int kt = 0; kt < 4; ++kt)
    nb[kt] = *reinterpret_cast<const float4*>(&brow[kv_lo + kt * 16]);
  int cur = 0;

  for (int t = 0; t < ntiles; ++t) {
    const int kv0 = kv_lo + t * 64;
    __syncthreads();            // buf[cur] staged AND nb loads drained
#pragma unroll
    for (int kt = 0; kt < 4; ++kt) cb[kt] = nb[kt];   // free: already drained

    if (t + 1 < ntiles) STAGE(cur ^ 1, kv0 + 64);
    // issue next tile's bias (consumed only after the NEXT barrier)
    const int nxt = (kv0 + 64 <= kv_last) ? kv0 + 64 : kv0;
#pragma unroll
    for (int kt = 0; kt < 4; ++kt)
      nb[kt] = *reinterpret_cast<const float4*>(&brow[nxt + kt * 16]);

    const bool active = (kv0 <= qw_hi) && (kv0 + 63 >= qw - WIN);
    if (active) {
      const char* Kl = (const char*)&KV[cur][0][0];
      const char* Vl = (const char*)&KV[cur][1][0];

      // ---- QK^T (swapped): C col=q(ql), row=token(4g+r within 16) ----
      f32x4 s[4];
#pragma unroll
      for (int kt = 0; kt < 4; ++kt) {
        bf16x8 ka = *reinterpret_cast<const bf16x8*>(Kl + (kt * 16 + ql) * 128 + ((g * 16) ^ swz));
        bf16x8 kb = *reinterpret_cast<const bf16x8*>(Kl + (kt * 16 + ql) * 128 + ((64 + g * 16) ^ swz));
        f32x4 acc = f32x4{0.f, 0.f, 0.f, 0.f};
        acc = __builtin_amdgcn_mfma_f32_16x16x32_bf16(ka, qf0, acc, 0, 0, 0);
        acc = __builtin_amdgcn_mfma_f32_16x16x32_bf16(kb, qf1, acc, 0, 0, 0);
        s[kt] = acc;
      }

      // ---- bias + mask + online softmax (cb already in registers) ----
      const bool full = (kv0 + 63 <= qw) && (qw_hi - kv0 <= WIN);
      float lmax = -INFINITY;
#pragma unroll
      for (int kt = 0; kt < 4; ++kt) {
        float bvr[4] = {cb[kt].x, cb[kt].y, cb[kt].z, cb[kt].w};
#pragma unroll
        for (int r = 0; r < 4; ++r) {
          int k = kv0 + kt * 16 + 4 * g + r;
          float xv = s[kt][r] + bvr[r];
          if (!full) {
            bool ok = (k <= qg) && ((qg - k) <= WIN);
            xv = ok ? xv : -INFINITY;
          }
          s[kt][r] = xv;
          lmax = fmaxf(lmax, xv);
        }
      }
      lmax = fmaxf(lmax, __shfl_xor(lmax, 16));
      lmax = fmaxf(lmax, __shfl_xor(lmax, 32));
      float mn = fmaxf(m, lmax);
      float corr = __expf(m - mn);
      m = mn;
      float ls = 0.f;
#pragma unroll
      for (int kt = 0; kt < 4; ++kt)
#pragma unroll
        for (int r = 0; r < 4; ++r) {
          float e = __expf(s[kt][r] - mn);
          s[kt][r] = e;
          ls += e;
        }
      ls += __shfl_xor(ls, 16);
      ls += __shfl_xor(ls, 32);
      l = l * corr + ls;
#pragma unroll
      for (int dt = 0; dt < 4; ++dt) {
        f32x4 tt = o[dt];
#pragma unroll
        for (int r = 0; r < 4; ++r) tt[r] *= corr;
        o[dt] = tt;
      }

      // ---- P -> LDS (row=q, swizzled), PV from LDS V^T ----
#pragma unroll
      for (int kt = 0; kt < 4; ++kt) {
        ushort4 pw;
        pw.x = f2bf(s[kt][0]); pw.y = f2bf(s[kt][1]);
        pw.z = f2bf(s[kt][2]); pw.w = f2bf(s[kt][3]);
        *reinterpret_cast<ushort4*>(Prow + ((kt * 32 + g * 8) ^ swz)) = pw;
      }
#pragma unroll
      for (int kb = 0; kb < 2; ++kb) {
        bf16x8 pf = *reinterpret_cast<const bf16x8*>(Prow + ((kb * 64 + g * 16) ^ swz));
#pragma unroll
        for (int dt = 0; dt < 4; ++dt) {
          bf16x8 vf = *reinterpret_cast<const bf16x8*>(Vl + (dt * 16 + ql) * 128 + ((kb * 64 + g * 16) ^ swz));
          o[dt] = __builtin_amdgcn_mfma_f32_16x16x32_bf16(vf, pf, o[dt], 0, 0, 0);
        }
      }
    }
    cur ^= 1;
  }

  // ---- finalize (no merge needed: each wave owns its q rows) ----
  float inv = (l > 0.f) ? 1.f / l : 0.f;
  u16* outbase = (blockIdx.z == 0) ? Ob : Odummy;
  u16* op = &outbase[(size_t)qg * EMB + h * HDIM];
#pragma unroll
  for (int dt = 0; dt < 4; ++dt) {
    ushort4 outv;
#pragma unroll
    for (int r = 0; r < 4; ++r) ((u16*)&outv)[r] = f2bf(o[dt][r] * inv);
    *reinterpret_cast<ushort4*>(op + dt * 16 + 4 * g) = outv;
  }
}

// --------------------------------------------------------------------------
extern "C" void kernel_launch(void* const* d_in, const int* in_sizes, int n_in,
                              void* d_out, int out_size, void* d_ws, size_t ws_size,
                              hipStream_t stream) {
  (void)in_sizes; (void)n_in; (void)out_size; (void)ws_size;
  const float* q  = (const float*)d_in[0];
  const float* k  = (const float*)d_in[1];
  const float* v  = (const float*)d_in[2];
  const float* pb = (const float*)d_in[3];
  const float* Wq = (const float*)d_in[4];
  const float* bq = (const float*)d_in[5];
  const float* Wk = (const float*)d_in[6];
  const float* bk = (const float*)d_in[7];
  const float* Wv = (const float*)d_in[8];
  const float* bv = (const float*)d_in[9];
  const float* Wo = (const float*)d_in[10];
  const float* bo = (const float*)d_in[11];
  float* out = (float*)d_out;

  const size_t SE = (size_t)S_LEN * EMB;
  const size_t EE = (size_t)EMB * EMB;
  u16* ws  = (u16*)d_ws;
  u16* qb  = ws;
  u16* kb  = qb + SE;
  u16* vb  = kb + SE;
  u16* wqb = vb + SE;
  u16* wkb = wqb + EE;
  u16* wvb = wkb + EE;
  u16* wob = wvb + EE;
  u16* Qp  = wob + EE;        // [H][S][D], pre-scaled 1/64
  u16* Kp  = Qp + SE;         // [H][S][D]
  u16* Vp  = Kp + SE;         // [S][E]
  u16* Vt  = Vp + SE;         // [H][D][S]
  u16* Ob  = Vt + SE;         // [S][E]
  u16* Odummy = Ob + SE;      // diagnostic replica sink

  conv_kernel<<<dim3(2048, 7), 256, 0, stream>>>(q, k, v, Wq, Wk, Wv, Wo,
                                                 qb, kb, vb, wqb, wkb, wvb, wob);
  proj_gemm<<<dim3(16, 8, 3), 256, 0, stream>>>(qb, wqb, bq, bk, bv, Qp);
  transpose_v<<<dim3(32, 64), 256, 0, stream>>>(Vp, Vt);
  attn_kernel<<<dim3(32, 16, 4), 256, 0, stream>>>(Qp, Kp, Vt, pb, Ob, Odummy);
  out_gemm<<<dim3(16, 8), 256, 0, stream>>>(Ob, wob, bo, out, out + SE);
}

// Round 7
// 121.954 us; speedup vs baseline: 1.6623x; 1.6623x over previous
//
#include <hip/hip_runtime.h>

typedef unsigned short u16;
typedef __bf16 bf16x8 __attribute__((ext_vector_type(8)));
typedef float f32x4 __attribute__((ext_vector_type(4)));

#define S_LEN 2048
#define EMB   1024
#define NHEAD 16
#define HDIM  64
#define WIN   1024

__device__ __forceinline__ u16 f2bf(float f) {
  unsigned u = __float_as_uint(f);
  u += 0x7FFFu + ((u >> 16) & 1u);   // round-to-nearest-even
  return (u16)(u >> 16);
}

// ---------------- fp32 -> bf16 conversion: 7 tensors, one launch ----------
__global__ __launch_bounds__(256) void conv_kernel(
    const float* __restrict__ p0, const float* __restrict__ p1,
    const float* __restrict__ p2, const float* __restrict__ p3,
    const float* __restrict__ p4, const float* __restrict__ p5,
    const float* __restrict__ p6,
    u16* __restrict__ o0, u16* __restrict__ o1, u16* __restrict__ o2,
    u16* __restrict__ o3, u16* __restrict__ o4, u16* __restrict__ o5,
    u16* __restrict__ o6) {
  const float* src; u16* dst; int n;
  switch (blockIdx.y) {
    case 0: src = p0; dst = o0; n = S_LEN * EMB; break;
    case 1: src = p1; dst = o1; n = S_LEN * EMB; break;
    case 2: src = p2; dst = o2; n = S_LEN * EMB; break;
    case 3: src = p3; dst = o3; n = EMB * EMB; break;
    case 4: src = p4; dst = o4; n = EMB * EMB; break;
    case 5: src = p5; dst = o5; n = EMB * EMB; break;
    default: src = p6; dst = o6; n = EMB * EMB; break;
  }
  int i = (blockIdx.x * 256 + threadIdx.x) * 4;
  if (i >= n) return;
  float4 v = *reinterpret_cast<const float4*>(src + i);
  ushort4 r;
  r.x = f2bf(v.x); r.y = f2bf(v.y); r.z = f2bf(v.z); r.w = f2bf(v.w);
  *reinterpret_cast<ushort4*>(dst + i) = r;
}

// ---------------- bf16 GEMM core: C[M,N] = A[M,K] @ W[N,K]^T --------------
// headMajor: bf16 out in [H][S][D] layout (for attention operand locality).
__device__ __forceinline__ void gemm128_core(
    const u16* __restrict__ A, const u16* __restrict__ W,
    const float* __restrict__ bias, float scale, int headMajor,
    u16* __restrict__ outB, float* __restrict__ outF0, float* __restrict__ outF1,
    int N, int K, int bm, int bn, u16* As, u16* Bs) {
  const int tid  = threadIdx.x;
  const int w    = tid >> 6;
  const int lane = tid & 63;
  const int wr = w >> 1, wc = w & 1;
  const int lr = lane & 15;
  const int ko = (lane >> 4) * 8;

  f32x4 acc[4][4];
#pragma unroll
  for (int i = 0; i < 4; ++i)
#pragma unroll
    for (int j = 0; j < 4; ++j) acc[i][j] = f32x4{0.f, 0.f, 0.f, 0.f};

  const int srow = lane >> 3;        // 0..7
  const int scol = (lane & 7) * 8;   // 0..56

  for (int k0 = 0; k0 < K; k0 += 64) {
    const u16* Ab = A + (size_t)bm * K + k0;
    const u16* Wb = W + (size_t)bn * K + k0;
#pragma unroll
    for (int c = 0; c < 4; ++c) {
      int s = w * 4 + c;
      __builtin_amdgcn_global_load_lds(
          (const __attribute__((address_space(1))) void*)(Ab + (size_t)(s * 8 + srow) * K + scol),
          (__attribute__((address_space(3))) void*)(As + s * 512), 16, 0, 0);
      __builtin_amdgcn_global_load_lds(
          (const __attribute__((address_space(1))) void*)(Wb + (size_t)(s * 8 + srow) * K + scol),
          (__attribute__((address_space(3))) void*)(Bs + s * 512), 16, 0, 0);
    }
    __syncthreads();
#pragma unroll
    for (int kk = 0; kk < 2; ++kk) {
      bf16x8 af[4], bfr[4];
#pragma unroll
      for (int mi = 0; mi < 4; ++mi)
        af[mi] = *reinterpret_cast<const bf16x8*>(&As[(wr * 64 + mi * 16 + lr) * 64 + kk * 32 + ko]);
#pragma unroll
      for (int ni = 0; ni < 4; ++ni)
        bfr[ni] = *reinterpret_cast<const bf16x8*>(&Bs[(wc * 64 + ni * 16 + lr) * 64 + kk * 32 + ko]);
#pragma unroll
      for (int mi = 0; mi < 4; ++mi)
#pragma unroll
        for (int ni = 0; ni < 4; ++ni)
          acc[mi][ni] = __builtin_amdgcn_mfma_f32_16x16x32_bf16(af[mi], bfr[ni], acc[mi][ni], 0, 0, 0);
    }
    __syncthreads();
  }

  const int cr = (lane >> 4) * 4;
  const int cc = lane & 15;
#pragma unroll
  for (int mi = 0; mi < 4; ++mi) {
#pragma unroll
    for (int ni = 0; ni < 4; ++ni) {
      int col = bn + wc * 64 + ni * 16 + cc;
      float bv = bias[col];
#pragma unroll
      for (int r = 0; r < 4; ++r) {
        int row = bm + wr * 64 + mi * 16 + cr + r;
        float val = (acc[mi][ni][r] + bv) * scale;
        if (outB) {
          size_t idx = headMajor
              ? (size_t)(col >> 6) * (S_LEN * HDIM) + (size_t)row * HDIM + (col & 63)
              : (size_t)row * N + col;
          outB[idx] = f2bf(val);
        } else {
          outF0[(size_t)row * N + col] = val;
          outF1[(size_t)row * N + col] = val;
        }
      }
    }
  }
}

// z=0: Q (head-major, pre-scaled 1/64); z=1: K (head-major); z=2: V (token-major)
__global__ __launch_bounds__(256) void proj_gemm(
    const u16* __restrict__ Abase, const u16* __restrict__ Wbase,
    const float* __restrict__ b0, const float* __restrict__ b1,
    const float* __restrict__ b2, u16* __restrict__ Obase) {
  __shared__ u16 As[128 * 64];
  __shared__ u16 Bs[128 * 64];
  const int z = blockIdx.z;
  const u16* A = Abase + (size_t)z * (S_LEN * EMB);
  const u16* W = Wbase + (size_t)z * (EMB * EMB);
  const float* bias = (z == 0) ? b0 : (z == 1 ? b1 : b2);
  u16* O = Obase + (size_t)z * (S_LEN * EMB);
  float scale = (z == 0) ? (1.0f / 64.0f) : 1.0f;
  gemm128_core(A, W, bias, scale, (z < 2) ? 1 : 0, O, nullptr, nullptr,
               EMB, EMB, blockIdx.x * 128, blockIdx.y * 128, As, Bs);
}

__global__ __launch_bounds__(256) void out_gemm(
    const u16* __restrict__ A, const u16* __restrict__ W,
    const float* __restrict__ bias, float* __restrict__ out0,
    float* __restrict__ out1) {
  __shared__ u16 As[128 * 64];
  __shared__ u16 Bs[128 * 64];
  gemm128_core(A, W, bias, 1.0f, 0, nullptr, out0, out1,
               EMB, EMB, blockIdx.x * 128, blockIdx.y * 128, As, Bs);
}

// ---------------- V transpose: Vp[S,E] -> Vt[E,S] == [H][D][S] ------------
__global__ __launch_bounds__(256) void transpose_v(
    const u16* __restrict__ in, u16* __restrict__ out) {
  __shared__ u16 tile[32][33];
  const int bx = blockIdx.x * 32;  // E base
  const int by = blockIdx.y * 32;  // S base
  const int tr = threadIdx.x >> 5;
  const int tc = threadIdx.x & 31;
#pragma unroll
  for (int i = 0; i < 4; ++i)
    tile[tr + i * 8][tc] = in[(size_t)(by + tr + i * 8) * EMB + bx + tc];
  __syncthreads();
#pragma unroll
  for (int i = 0; i < 4; ++i)
    out[(size_t)(bx + tr + i * 8) * S_LEN + by + tc] = tile[tc][tr + i * 8];
}

// ---------------- flash attention: q-split waves, KV parity-split blocks --
// Grid (32, 16, 2): 1024 blocks -> 4 blocks/CU (matches 40KB LDS cap), the
// occupancy regime the round-6 replication experiment measured at ~2x the
// per-work throughput of 2 blocks/CU. blockIdx.z picks KV tiles of matching
// parity (t % 2 == z); each block writes unnormalized fp32 partials (O,m,l);
// a small merge kernel combines the two halves.
__global__ __launch_bounds__(256, 4) void attn_kernel(
    const u16* __restrict__ Qp, const u16* __restrict__ Kp,
    const u16* __restrict__ Vt, const float* __restrict__ pbias,
    float* __restrict__ Op, float* __restrict__ Mp, float* __restrict__ Lp) {
  __shared__ u16 KV[2][2][64 * 64];   // [buf][0=K tile / 1=V^T tile]
  __shared__ u16 Pb[4][16 * 64];      // per-wave P buffer (swizzled rows)

  const int tid  = threadIdx.x;
  const int w    = tid >> 6;
  const int lane = tid & 63;
  const int h  = blockIdx.y;
  const int z  = blockIdx.z;
  const int q0 = (gridDim.x - 1 - blockIdx.x) * 64;  // long blocks first
  const int ql = lane & 15;
  const int g  = lane >> 4;
  const int qw = q0 + w * 16;              // this wave's q sub-tile base
  const int qg = qw + ql;                  // this lane's q row

  const u16* Kh  = Kp + (size_t)h * (S_LEN * HDIM);
  const u16* Vth = Vt + (size_t)h * (HDIM * S_LEN);

  // Q fragments (B-operand: col=q, k-elem d=g*8+j), head-major load
  const u16* Qrow = Qp + (size_t)h * (S_LEN * HDIM) + (size_t)qg * HDIM;
  bf16x8 qf0 = *reinterpret_cast<const bf16x8*>(&Qrow[g * 8]);
  bf16x8 qf1 = *reinterpret_cast<const bf16x8*>(&Qrow[32 + g * 8]);

  f32x4 o[4];
#pragma unroll
  for (int i = 0; i < 4; ++i) o[i] = f32x4{0.f, 0.f, 0.f, 0.f};
  float m = -1e30f, l = 0.f;

  const float* brow = pbias + (size_t)h * S_LEN * S_LEN + (size_t)qg * S_LEN + 4 * g;

  int kv_lo = q0 - WIN; if (kv_lo < 0) kv_lo = 0; kv_lo &= ~63;
  const int ntiles = ((q0 + 63 - kv_lo) >> 6) + 1;
  const int nmine  = (ntiles - z + 1) >> 1;    // tiles with t%2==z
  const int kv_first = kv_lo + z * 64;
  const int qw_hi = qw + 15;

  const int swz = (ql & 7) << 4;
  char* Prow = (char*)&Pb[w][0] + ql * 128;

  // stage K-tile + V^T-tile for kv0 into buf (wave w covers rows w*16..+15)
  auto STAGE = [&](int buf, int kv0) {
    u16* Kd = &KV[buf][0][(w * 16) * 64];
    u16* Vd = &KV[buf][1][(w * 16) * 64];
#pragma unroll
    for (int n = 0; n < 2; ++n) {
      int r  = w * 16 + n * 8 + (lane >> 3);
      int cp = (lane & 7) ^ (r & 7);
      __builtin_amdgcn_global_load_lds(
          (const __attribute__((address_space(1))) void*)(Kh + (size_t)(kv0 + r) * HDIM + cp * 8),
          (__attribute__((address_space(3))) void*)(Kd + n * 512), 16, 0, 0);
      __builtin_amdgcn_global_load_lds(
          (const __attribute__((address_space(1))) void*)(Vth + (size_t)r * S_LEN + kv0 + cp * 8),
          (__attribute__((address_space(3))) void*)(Vd + n * 512), 16, 0, 0);
    }
  };

  if (nmine > 0) {
    STAGE(0, kv_first);
    float4 nb[4], cb[4];
#pragma unroll
    for (int kt = 0; kt < 4; ++kt)
      nb[kt] = *reinterpret_cast<const float4*>(&brow[kv_first + kt * 16]);
    int cur = 0;

    for (int i = 0; i < nmine; ++i) {
      const int kv0 = kv_first + i * 128;          // parity stride = 2 tiles
      __syncthreads();            // buf[cur] staged AND nb loads drained
#pragma unroll
      for (int kt = 0; kt < 4; ++kt) cb[kt] = nb[kt];

      if (i + 1 < nmine) STAGE(cur ^ 1, kv0 + 128);
      const int nxt = (i + 1 < nmine) ? kv0 + 128 : kv0;
#pragma unroll
      for (int kt = 0; kt < 4; ++kt)
        nb[kt] = *reinterpret_cast<const float4*>(&brow[nxt + kt * 16]);

      const bool active = (kv0 <= qw_hi) && (kv0 + 63 >= qw - WIN);
      if (active) {
        const char* Kl = (const char*)&KV[cur][0][0];
        const char* Vl = (const char*)&KV[cur][1][0];

        // ---- QK^T (swapped): C col=q(ql), row=token(4g+r within 16) ----
        f32x4 s[4];
#pragma unroll
        for (int kt = 0; kt < 4; ++kt) {
          bf16x8 ka = *reinterpret_cast<const bf16x8*>(Kl + (kt * 16 + ql) * 128 + ((g * 16) ^ swz));
          bf16x8 kb = *reinterpret_cast<const bf16x8*>(Kl + (kt * 16 + ql) * 128 + ((64 + g * 16) ^ swz));
          f32x4 acc = f32x4{0.f, 0.f, 0.f, 0.f};
          acc = __builtin_amdgcn_mfma_f32_16x16x32_bf16(ka, qf0, acc, 0, 0, 0);
          acc = __builtin_amdgcn_mfma_f32_16x16x32_bf16(kb, qf1, acc, 0, 0, 0);
          s[kt] = acc;
        }

        // ---- bias + mask + online softmax (cb already in registers) ----
        const bool full = (kv0 + 63 <= qw) && (qw_hi - kv0 <= WIN);
        float lmax = -INFINITY;
#pragma unroll
        for (int kt = 0; kt < 4; ++kt) {
          float bvr[4] = {cb[kt].x, cb[kt].y, cb[kt].z, cb[kt].w};
#pragma unroll
          for (int r = 0; r < 4; ++r) {
            int k = kv0 + kt * 16 + 4 * g + r;
            float xv = s[kt][r] + bvr[r];
            if (!full) {
              bool ok = (k <= qg) && ((qg - k) <= WIN);
              xv = ok ? xv : -INFINITY;
            }
            s[kt][r] = xv;
            lmax = fmaxf(lmax, xv);
          }
        }
        lmax = fmaxf(lmax, __shfl_xor(lmax, 16));
        lmax = fmaxf(lmax, __shfl_xor(lmax, 32));
        float mn = fmaxf(m, lmax);
        float corr = __expf(m - mn);
        m = mn;
        float ls = 0.f;
#pragma unroll
        for (int kt = 0; kt < 4; ++kt)
#pragma unroll
          for (int r = 0; r < 4; ++r) {
            float e = __expf(s[kt][r] - mn);
            s[kt][r] = e;
            ls += e;
          }
        ls += __shfl_xor(ls, 16);
        ls += __shfl_xor(ls, 32);
        l = l * corr + ls;
#pragma unroll
        for (int dt = 0; dt < 4; ++dt) {
          f32x4 tt = o[dt];
#pragma unroll
          for (int r = 0; r < 4; ++r) tt[r] *= corr;
          o[dt] = tt;
        }

        // ---- P -> LDS (row=q, swizzled), PV from LDS V^T ----
#pragma unroll
        for (int kt = 0; kt < 4; ++kt) {
          ushort4 pw;
          pw.x = f2bf(s[kt][0]); pw.y = f2bf(s[kt][1]);
          pw.z = f2bf(s[kt][2]); pw.w = f2bf(s[kt][3]);
          *reinterpret_cast<ushort4*>(Prow + ((kt * 32 + g * 8) ^ swz)) = pw;
        }
#pragma unroll
        for (int kb = 0; kb < 2; ++kb) {
          bf16x8 pf = *reinterpret_cast<const bf16x8*>(Prow + ((kb * 64 + g * 16) ^ swz));
#pragma unroll
          for (int dt = 0; dt < 4; ++dt) {
            bf16x8 vf = *reinterpret_cast<const bf16x8*>(Vl + (dt * 16 + ql) * 128 + ((kb * 64 + g * 16) ^ swz));
            o[dt] = __builtin_amdgcn_mfma_f32_16x16x32_bf16(vf, pf, o[dt], 0, 0, 0);
          }
        }
      }
      cur ^= 1;
    }
  }

  // ---- write unnormalized partials for this KV half ----
  const size_t p = ((size_t)z * NHEAD + h) * S_LEN + qg;
  if (lane < 16) { Mp[p] = m; Lp[p] = l; }
#pragma unroll
  for (int dt = 0; dt < 4; ++dt)
    *reinterpret_cast<f32x4*>(&Op[p * HDIM + dt * 16 + 4 * g]) = o[dt];
}

// ---------------- merge the two KV-half partials -> bf16 Ob [S][E] --------
__global__ __launch_bounds__(256) void merge_kernel(
    const float* __restrict__ Op, const float* __restrict__ Mp,
    const float* __restrict__ Lp, u16* __restrict__ Ob) {
  const int pr = blockIdx.x * 4 + (threadIdx.x >> 6);  // pair = h*S_LEN + q
  const int d  = threadIdx.x & 63;
  const int q  = pr & (S_LEN - 1);
  const int h  = pr >> 11;
  const size_t HALF = (size_t)NHEAD * S_LEN;
  float m0 = Mp[pr], m1 = Mp[HALF + pr];
  float l0 = Lp[pr], l1 = Lp[HALF + pr];
  float M  = fmaxf(m0, m1);
  float w0 = __expf(m0 - M), w1 = __expf(m1 - M);
  float L  = l0 * w0 + l1 * w1;
  float inv = (L > 0.f) ? 1.f / L : 0.f;
  float v = (Op[(size_t)pr * HDIM + d] * w0 + Op[(HALF + pr) * HDIM + d] * w1) * inv;
  Ob[(size_t)q * EMB + h * HDIM + d] = f2bf(v);
}

// --------------------------------------------------------------------------
extern "C" void kernel_launch(void* const* d_in, const int* in_sizes, int n_in,
                              void* d_out, int out_size, void* d_ws, size_t ws_size,
                              hipStream_t stream) {
  (void)in_sizes; (void)n_in; (void)out_size; (void)ws_size;
  const float* q  = (const float*)d_in[0];
  const float* k  = (const float*)d_in[1];
  const float* v  = (const float*)d_in[2];
  const float* pb = (const float*)d_in[3];
  const float* Wq = (const float*)d_in[4];
  const float* bq = (const float*)d_in[5];
  const float* Wk = (const float*)d_in[6];
  const float* bk = (const float*)d_in[7];
  const float* Wv = (const float*)d_in[8];
  const float* bv = (const float*)d_in[9];
  const float* Wo = (const float*)d_in[10];
  const float* bo = (const float*)d_in[11];
  float* out = (float*)d_out;

  const size_t SE = (size_t)S_LEN * EMB;
  const size_t EE = (size_t)EMB * EMB;
  u16* ws  = (u16*)d_ws;
  u16* qb  = ws;
  u16* kb  = qb + SE;
  u16* vb  = kb + SE;
  u16* wqb = vb + SE;
  u16* wkb = wqb + EE;
  u16* wvb = wkb + EE;
  u16* wob = wvb + EE;
  u16* Qp  = wob + EE;        // [H][S][D], pre-scaled 1/64
  u16* Kp  = Qp + SE;         // [H][S][D]
  u16* Vp  = Kp + SE;         // [S][E]
  u16* Vt  = Vp + SE;         // [H][D][S]
  u16* Ob  = Vt + SE;         // [S][E]
  float* Op = (float*)(Ob + SE);                 // [2][H][S][D] fp32 partials
  float* Mp = Op + (size_t)2 * NHEAD * S_LEN * HDIM;
  float* Lp = Mp + (size_t)2 * NHEAD * S_LEN;

  conv_kernel<<<dim3(2048, 7), 256, 0, stream>>>(q, k, v, Wq, Wk, Wv, Wo,
                                                 qb, kb, vb, wqb, wkb, wvb, wob);
  proj_gemm<<<dim3(16, 8, 3), 256, 0, stream>>>(qb, wqb, bq, bk, bv, Qp);
  transpose_v<<<dim3(32, 64), 256, 0, stream>>>(Vp, Vt);
  attn_kernel<<<dim3(32, 16, 2), 256, 0, stream>>>(Qp, Kp, Vt, pb, Op, Mp, Lp);
  merge_kernel<<<dim3(NHEAD * S_LEN / 4), 256, 0, stream>>>(Op, Mp, Lp, Ob);
  out_gemm<<<dim3(16, 8), 256, 0, stream>>>(Ob, wob, bo, out, out + SE);
}

// Round 8
// 103.832 us; speedup vs baseline: 1.9524x; 1.1745x over previous
//
#include <hip/hip_runtime.h>

typedef unsigned short u16;
typedef __bf16 bf16x8 __attribute__((ext_vector_type(8)));
typedef float f32x4 __attribute__((ext_vector_type(4)));

#define S_LEN 2048
#define EMB   1024
#define NHEAD 16
#define HDIM  64
#define WIN   1024

__device__ __forceinline__ u16 f2bf(float f) {
  unsigned u = __float_as_uint(f);
  u += 0x7FFFu + ((u >> 16) & 1u);   // round-to-nearest-even
  return (u16)(u >> 16);
}

// ---------------- fp32 -> bf16 conversion: 7 tensors, one launch ----------
__global__ __launch_bounds__(256) void conv_kernel(
    const float* __restrict__ p0, const float* __restrict__ p1,
    const float* __restrict__ p2, const float* __restrict__ p3,
    const float* __restrict__ p4, const float* __restrict__ p5,
    const float* __restrict__ p6,
    u16* __restrict__ o0, u16* __restrict__ o1, u16* __restrict__ o2,
    u16* __restrict__ o3, u16* __restrict__ o4, u16* __restrict__ o5,
    u16* __restrict__ o6) {
  const float* src; u16* dst; int n;
  switch (blockIdx.y) {
    case 0: src = p0; dst = o0; n = S_LEN * EMB; break;
    case 1: src = p1; dst = o1; n = S_LEN * EMB; break;
    case 2: src = p2; dst = o2; n = S_LEN * EMB; break;
    case 3: src = p3; dst = o3; n = EMB * EMB; break;
    case 4: src = p4; dst = o4; n = EMB * EMB; break;
    case 5: src = p5; dst = o5; n = EMB * EMB; break;
    default: src = p6; dst = o6; n = EMB * EMB; break;
  }
  int i = (blockIdx.x * 256 + threadIdx.x) * 4;
  if (i >= n) return;
  float4 v = *reinterpret_cast<const float4*>(src + i);
  ushort4 r;
  r.x = f2bf(v.x); r.y = f2bf(v.y); r.z = f2bf(v.z); r.w = f2bf(v.w);
  *reinterpret_cast<ushort4*>(dst + i) = r;
}

// ------- bf16 GEMM core, 128x64 tile: C[M,N] = A[M,K] @ W[N,K]^T ----------
// 4 waves as 2x2 (wave covers 64 rows x 32 cols, acc[4][2]). BK=64.
// 24KB LDS -> high blocks/CU; grids sized for >=1 block/CU.
__device__ __forceinline__ void gemm_128x64_core(
    const u16* __restrict__ A, const u16* __restrict__ W,
    const float* __restrict__ bias, float scale, int headMajor,
    u16* __restrict__ outB, float* __restrict__ outF0, float* __restrict__ outF1,
    int N, int K, int bm, int bn, u16* As, u16* Bs) {
  const int tid  = threadIdx.x;
  const int w    = tid >> 6;
  const int lane = tid & 63;
  const int wr = w >> 1, wc = w & 1;
  const int lr = lane & 15;
  const int ko = (lane >> 4) * 8;

  f32x4 acc[4][2];
#pragma unroll
  for (int i = 0; i < 4; ++i)
#pragma unroll
    for (int j = 0; j < 2; ++j) acc[i][j] = f32x4{0.f, 0.f, 0.f, 0.f};

  const int srow = lane >> 3;        // 0..7
  const int scol = (lane & 7) * 8;   // 0..56

  for (int k0 = 0; k0 < K; k0 += 64) {
    const u16* Ab = A + (size_t)bm * K + k0;
    const u16* Wb = W + (size_t)bn * K + k0;
#pragma unroll
    for (int c = 0; c < 4; ++c) {      // A: 16 segments of 8 rows
      int s = w * 4 + c;
      __builtin_amdgcn_global_load_lds(
          (const __attribute__((address_space(1))) void*)(Ab + (size_t)(s * 8 + srow) * K + scol),
          (__attribute__((address_space(3))) void*)(As + s * 512), 16, 0, 0);
    }
#pragma unroll
    for (int c = 0; c < 2; ++c) {      // B: 8 segments of 8 rows
      int s = w * 2 + c;
      __builtin_amdgcn_global_load_lds(
          (const __attribute__((address_space(1))) void*)(Wb + (size_t)(s * 8 + srow) * K + scol),
          (__attribute__((address_space(3))) void*)(Bs + s * 512), 16, 0, 0);
    }
    __syncthreads();
#pragma unroll
    for (int kk = 0; kk < 2; ++kk) {
      bf16x8 af[4], bfr[2];
#pragma unroll
      for (int mi = 0; mi < 4; ++mi)
        af[mi] = *reinterpret_cast<const bf16x8*>(&As[(wr * 64 + mi * 16 + lr) * 64 + kk * 32 + ko]);
#pragma unroll
      for (int ni = 0; ni < 2; ++ni)
        bfr[ni] = *reinterpret_cast<const bf16x8*>(&Bs[(wc * 32 + ni * 16 + lr) * 64 + kk * 32 + ko]);
#pragma unroll
      for (int mi = 0; mi < 4; ++mi)
#pragma unroll
        for (int ni = 0; ni < 2; ++ni)
          acc[mi][ni] = __builtin_amdgcn_mfma_f32_16x16x32_bf16(af[mi], bfr[ni], acc[mi][ni], 0, 0, 0);
    }
    __syncthreads();
  }

  const int cr = (lane >> 4) * 4;
  const int cc = lane & 15;
#pragma unroll
  for (int mi = 0; mi < 4; ++mi) {
#pragma unroll
    for (int ni = 0; ni < 2; ++ni) {
      int col = bn + wc * 32 + ni * 16 + cc;
      float bv = bias[col];
#pragma unroll
      for (int r = 0; r < 4; ++r) {
        int row = bm + wr * 64 + mi * 16 + cr + r;
        float val = (acc[mi][ni][r] + bv) * scale;
        if (outB) {
          size_t idx = headMajor
              ? (size_t)(col >> 6) * (S_LEN * HDIM) + (size_t)row * HDIM + (col & 63)
              : (size_t)row * N + col;
          outB[idx] = f2bf(val);
        } else {
          outF0[(size_t)row * N + col] = val;
          outF1[(size_t)row * N + col] = val;
        }
      }
    }
  }
}

// z=0: Q (head-major, pre-scaled 1/64); z=1: K (head-major); z=2: V (token-major)
__global__ __launch_bounds__(256, 4) void proj_gemm(
    const u16* __restrict__ Abase, const u16* __restrict__ Wbase,
    const float* __restrict__ b0, const float* __restrict__ b1,
    const float* __restrict__ b2, u16* __restrict__ Obase) {
  __shared__ u16 As[128 * 64];
  __shared__ u16 Bs[64 * 64];
  const int z = blockIdx.z;
  const u16* A = Abase + (size_t)z * (S_LEN * EMB);
  const u16* W = Wbase + (size_t)z * (EMB * EMB);
  const float* bias = (z == 0) ? b0 : (z == 1 ? b1 : b2);
  u16* O = Obase + (size_t)z * (S_LEN * EMB);
  float scale = (z == 0) ? (1.0f / 64.0f) : 1.0f;
  gemm_128x64_core(A, W, bias, scale, (z < 2) ? 1 : 0, O, nullptr, nullptr,
                   EMB, EMB, blockIdx.x * 128, blockIdx.y * 64, As, Bs);
}

__global__ __launch_bounds__(256, 4) void out_gemm(
    const u16* __restrict__ A, const u16* __restrict__ W,
    const float* __restrict__ bias, float* __restrict__ out0,
    float* __restrict__ out1) {
  __shared__ u16 As[128 * 64];
  __shared__ u16 Bs[64 * 64];
  gemm_128x64_core(A, W, bias, 1.0f, 0, nullptr, out0, out1,
                   EMB, EMB, blockIdx.x * 128, blockIdx.y * 64, As, Bs);
}

// ---------------- V transpose: Vp[S,E] -> Vt[E,S] == [H][D][S] ------------
__global__ __launch_bounds__(256) void transpose_v(
    const u16* __restrict__ in, u16* __restrict__ out) {
  __shared__ u16 tile[32][33];
  const int bx = blockIdx.x * 32;  // E base
  const int by = blockIdx.y * 32;  // S base
  const int tr = threadIdx.x >> 5;
  const int tc = threadIdx.x & 31;
#pragma unroll
  for (int i = 0; i < 4; ++i)
    tile[tr + i * 8][tc] = in[(size_t)(by + tr + i * 8) * EMB + bx + tc];
  __syncthreads();
#pragma unroll
  for (int i = 0; i < 4; ++i)
    out[(size_t)(bx + tr + i * 8) * S_LEN + by + tc] = tile[tc][tr + i * 8];
}

// ---------------- flash attention: q-split waves, LDS-staged K/V ----------
// Round-7 core WITHOUT the KV parity split: grid (32,16), 64 q-rows/block,
// direct bf16 Ob write. Bias double-buffered ACROSS barriers: bias(t+1) is
// issued right after barrier t and consumed after barrier t+1, so its HBM
// latency hides under a full tile of compute (QK+softmax+PV), and the
// barrier's vmcnt-drain is the synchronization.
__global__ __launch_bounds__(256, 4) void attn_kernel(
    const u16* __restrict__ Qp, const u16* __restrict__ Kp,
    const u16* __restrict__ Vt, const float* __restrict__ pbias,
    u16* __restrict__ Ob) {
  __shared__ u16 KV[2][2][64 * 64];   // [buf][0=K tile / 1=V^T tile]
  __shared__ u16 Pb[4][16 * 64];      // per-wave P buffer (swizzled rows)

  const int tid  = threadIdx.x;
  const int w    = tid >> 6;
  const int lane = tid & 63;
  const int h  = blockIdx.y;
  const int q0 = (gridDim.x - 1 - blockIdx.x) * 64;  // long blocks first
  const int ql = lane & 15;
  const int g  = lane >> 4;
  const int qw = q0 + w * 16;              // this wave's q sub-tile base
  const int qg = qw + ql;                  // this lane's q row

  const u16* Kh  = Kp + (size_t)h * (S_LEN * HDIM);
  const u16* Vth = Vt + (size_t)h * (HDIM * S_LEN);

  // Q fragments (B-operand: col=q, k-elem d=g*8+j), head-major load
  const u16* Qrow = Qp + (size_t)h * (S_LEN * HDIM) + (size_t)qg * HDIM;
  bf16x8 qf0 = *reinterpret_cast<const bf16x8*>(&Qrow[g * 8]);
  bf16x8 qf1 = *reinterpret_cast<const bf16x8*>(&Qrow[32 + g * 8]);

  f32x4 o[4];
#pragma unroll
  for (int i = 0; i < 4; ++i) o[i] = f32x4{0.f, 0.f, 0.f, 0.f};
  float m = -1e30f, l = 0.f;

  const float* brow = pbias + (size_t)h * S_LEN * S_LEN + (size_t)qg * S_LEN + 4 * g;

  int kv_lo = q0 - WIN; if (kv_lo < 0) kv_lo = 0; kv_lo &= ~63;
  const int ntiles = ((q0 + 63 - kv_lo) >> 6) + 1;
  const int kv_last = kv_lo + (ntiles - 1) * 64;
  const int qw_hi = qw + 15;

  const int swz = (ql & 7) << 4;
  char* Prow = (char*)&Pb[w][0] + ql * 128;

  // stage K-tile + V^T-tile for kv0 into buf (wave w covers rows w*16..+15)
  auto STAGE = [&](int buf, int kv0) {
    u16* Kd = &KV[buf][0][(w * 16) * 64];
    u16* Vd = &KV[buf][1][(w * 16) * 64];
#pragma unroll
    for (int n = 0; n < 2; ++n) {
      int r  = w * 16 + n * 8 + (lane >> 3);
      int cp = (lane & 7) ^ (r & 7);
      __builtin_amdgcn_global_load_lds(
          (const __attribute__((address_space(1))) void*)(Kh + (size_t)(kv0 + r) * HDIM + cp * 8),
          (__attribute__((address_space(3))) void*)(Kd + n * 512), 16, 0, 0);
      __builtin_amdgcn_global_load_lds(
          (const __attribute__((address_space(1))) void*)(Vth + (size_t)r * S_LEN + kv0 + cp * 8),
          (__attribute__((address_space(3))) void*)(Vd + n * 512), 16, 0, 0);
    }
  };

  STAGE(0, kv_lo);
  float4 nb[4], cb[4];
#pragma unroll
  for (int kt = 0; kt < 4; ++kt)
    nb[kt] = *reinterpret_cast<const float4*>(&brow[kv_lo + kt * 16]);
  int cur = 0;

  for (int t = 0; t < ntiles; ++t) {
    const int kv0 = kv_lo + t * 64;
    __syncthreads();            // buf[cur] staged AND nb loads drained
#pragma unroll
    for (int kt = 0; kt < 4; ++kt) cb[kt] = nb[kt];

    if (t + 1 < ntiles) STAGE(cur ^ 1, kv0 + 64);
    const int nxt = (kv0 + 64 <= kv_last) ? kv0 + 64 : kv0;
#pragma unroll
    for (int kt = 0; kt < 4; ++kt)
      nb[kt] = *reinterpret_cast<const float4*>(&brow[nxt + kt * 16]);

    const bool active = (kv0 <= qw_hi) && (kv0 + 63 >= qw - WIN);
    if (active) {
      const char* Kl = (const char*)&KV[cur][0][0];
      const char* Vl = (const char*)&KV[cur][1][0];

      // ---- QK^T (swapped): C col=q(ql), row=token(4g+r within 16) ----
      f32x4 s[4];
#pragma unroll
      for (int kt = 0; kt < 4; ++kt) {
        bf16x8 ka = *reinterpret_cast<const bf16x8*>(Kl + (kt * 16 + ql) * 128 + ((g * 16) ^ swz));
        bf16x8 kb = *reinterpret_cast<const bf16x8*>(Kl + (kt * 16 + ql) * 128 + ((64 + g * 16) ^ swz));
        f32x4 acc = f32x4{0.f, 0.f, 0.f, 0.f};
        acc = __builtin_amdgcn_mfma_f32_16x16x32_bf16(ka, qf0, acc, 0, 0, 0);
        acc = __builtin_amdgcn_mfma_f32_16x16x32_bf16(kb, qf1, acc, 0, 0, 0);
        s[kt] = acc;
      }

      // ---- bias + mask + online softmax (cb already in registers) ----
      const bool full = (kv0 + 63 <= qw) && (qw_hi - kv0 <= WIN);
      float lmax = -INFINITY;
#pragma unroll
      for (int kt = 0; kt < 4; ++kt) {
        float bvr[4] = {cb[kt].x, cb[kt].y, cb[kt].z, cb[kt].w};
#pragma unroll
        for (int r = 0; r < 4; ++r) {
          int k = kv0 + kt * 16 + 4 * g + r;
          float xv = s[kt][r] + bvr[r];
          if (!full) {
            bool ok = (k <= qg) && ((qg - k) <= WIN);
            xv = ok ? xv : -INFINITY;
          }
          s[kt][r] = xv;
          lmax = fmaxf(lmax, xv);
        }
      }
      lmax = fmaxf(lmax, __shfl_xor(lmax, 16));
      lmax = fmaxf(lmax, __shfl_xor(lmax, 32));
      float mn = fmaxf(m, lmax);
      float corr = __expf(m - mn);
      m = mn;
      float ls = 0.f;
#pragma unroll
      for (int kt = 0; kt < 4; ++kt)
#pragma unroll
        for (int r = 0; r < 4; ++r) {
          float e = __expf(s[kt][r] - mn);
          s[kt][r] = e;
          ls += e;
        }
      ls += __shfl_xor(ls, 16);
      ls += __shfl_xor(ls, 32);
      l = l * corr + ls;
#pragma unroll
      for (int dt = 0; dt < 4; ++dt) {
        f32x4 tt = o[dt];
#pragma unroll
        for (int r = 0; r < 4; ++r) tt[r] *= corr;
        o[dt] = tt;
      }

      // ---- P -> LDS (row=q, swizzled), PV from LDS V^T ----
#pragma unroll
      for (int kt = 0; kt < 4; ++kt) {
        ushort4 pw;
        pw.x = f2bf(s[kt][0]); pw.y = f2bf(s[kt][1]);
        pw.z = f2bf(s[kt][2]); pw.w = f2bf(s[kt][3]);
        *reinterpret_cast<ushort4*>(Prow + ((kt * 32 + g * 8) ^ swz)) = pw;
      }
#pragma unroll
      for (int kb = 0; kb < 2; ++kb) {
        bf16x8 pf = *reinterpret_cast<const bf16x8*>(Prow + ((kb * 64 + g * 16) ^ swz));
#pragma unroll
        for (int dt = 0; dt < 4; ++dt) {
          bf16x8 vf = *reinterpret_cast<const bf16x8*>(Vl + (dt * 16 + ql) * 128 + ((kb * 64 + g * 16) ^ swz));
          o[dt] = __builtin_amdgcn_mfma_f32_16x16x32_bf16(vf, pf, o[dt], 0, 0, 0);
        }
      }
    }
    cur ^= 1;
  }

  // ---- finalize (each wave owns its q rows) ----
  float inv = (l > 0.f) ? 1.f / l : 0.f;
  u16* op = &Ob[(size_t)qg * EMB + h * HDIM];
#pragma unroll
  for (int dt = 0; dt < 4; ++dt) {
    ushort4 outv;
#pragma unroll
    for (int r = 0; r < 4; ++r) ((u16*)&outv)[r] = f2bf(o[dt][r] * inv);
    *reinterpret_cast<ushort4*>(op + dt * 16 + 4 * g) = outv;
  }
}

// --------------------------------------------------------------------------
extern "C" void kernel_launch(void* const* d_in, const int* in_sizes, int n_in,
                              void* d_out, int out_size, void* d_ws, size_t ws_size,
                              hipStream_t stream) {
  (void)in_sizes; (void)n_in; (void)out_size; (void)ws_size;
  const float* q  = (const float*)d_in[0];
  const float* k  = (const float*)d_in[1];
  const float* v  = (const float*)d_in[2];
  const float* pb = (const float*)d_in[3];
  const float* Wq = (const float*)d_in[4];
  const float* bq = (const float*)d_in[5];
  const float* Wk = (const float*)d_in[6];
  const float* bk = (const float*)d_in[7];
  const float* Wv = (const float*)d_in[8];
  const float* bv = (const float*)d_in[9];
  const float* Wo = (const float*)d_in[10];
  const float* bo = (const float*)d_in[11];
  float* out = (float*)d_out;

  const size_t SE = (size_t)S_LEN * EMB;
  const size_t EE = (size_t)EMB * EMB;
  u16* ws  = (u16*)d_ws;
  u16* qb  = ws;
  u16* kb  = qb + SE;
  u16* vb  = kb + SE;
  u16* wqb = vb + SE;
  u16* wkb = wqb + EE;
  u16* wvb = wkb + EE;
  u16* wob = wvb + EE;
  u16* Qp  = wob + EE;        // [H][S][D], pre-scaled 1/64
  u16* Kp  = Qp + SE;         // [H][S][D]
  u16* Vp  = Kp + SE;         // [S][E]
  u16* Vt  = Vp + SE;         // [H][D][S]
  u16* Ob  = Vt + SE;         // [S][E]

  conv_kernel<<<dim3(2048, 7), 256, 0, stream>>>(q, k, v, Wq, Wk, Wv, Wo,
                                                 qb, kb, vb, wqb, wkb, wvb, wob);
  proj_gemm<<<dim3(16, 16, 3), 256, 0, stream>>>(qb, wqb, bq, bk, bv, Qp);
  transpose_v<<<dim3(32, 64), 256, 0, stream>>>(Vp, Vt);
  attn_kernel<<<dim3(32, 16), 256, 0, stream>>>(Qp, Kp, Vt, pb, Ob);
  out_gemm<<<dim3(16, 16), 256, 0, stream>>>(Ob, wob, bo, out, out + SE);
}